// Round 10
// baseline (243.581 us; speedup 1.0000x reference)
//
#include <hip/hip_runtime.h>
#include <hip/hip_bf16.h>

#define Bb 4
#define Cc 96
#define Hh 256
#define Ww 512
#define OC 192
#define HO 128
#define WO 256
#define Gg 16
#define CPG 6

typedef __attribute__((ext_vector_type(4))) float f32x4;
typedef __attribute__((ext_vector_type(8))) short bf16x8;
typedef __attribute__((ext_vector_type(4))) short bf16x4;

static __device__ __forceinline__ ushort f2b(float f) {
    __hip_bfloat16 h = __float2bfloat16(f);
    return *reinterpret_cast<ushort*>(&h);
}
static __device__ __forceinline__ float b2f(ushort u) {
    unsigned int v = ((unsigned int)u) << 16;
    return __builtin_bit_cast(float, v);
}

// ---------------------------------------------------------------------------
// Pack w1, MFMA fragment order, klocal = q*8 + j (verified R7).
// ---------------------------------------------------------------------------
__global__ __launch_bounds__(64) void pack_w1(const float* __restrict__ w1,
                                              ushort* __restrict__ apack) {
    const int blk = blockIdx.x;      // 27*12
    const int k0 = blk / 12;
    const int mf = blk % 12;
    const int lane = threadIdx.x;
    const int m = mf * 16 + (lane & 15);
    const int chunk = k0 / 9;
    const int tap = k0 % 9;
    ushort* dst = apack + (((size_t)(k0 * 12 + mf) * 64) + lane) * 8;
#pragma unroll
    for (int j = 0; j < 8; ++j) {
        const int klocal = ((lane >> 4) << 3) + j;
        const int ic = chunk * 32 + klocal;
        dst[j] = f2b(w1[(size_t)(m * Cc + ic) * 9 + tap]);
    }
}

// ---------------------------------------------------------------------------
// Pack w2, softmax-group row permutation (verified R5) + klocal = q*8+j (R7).
// ---------------------------------------------------------------------------
__global__ __launch_bounds__(64) void pack_w2(const float* __restrict__ w2,
                                              ushort* __restrict__ w2p) {
    const int blk = blockIdx.x;      // 6*9
    const int ks = blk / 9;
    const int mf = blk % 9;
    const int lane = threadIdx.x;
    const int X = lane & 15;
    const int qq = X >> 2;
    const int rr = X & 3;
    const int s = mf * 4 + rr;
    const int g = qq * 4 + s / 9;
    const int k = s % 9;
    const int m = g * 9 + k;
    ushort* dst = w2p + (((size_t)(ks * 9 + mf) * 64) + lane) * 8;
#pragma unroll
    for (int j = 0; j < 8; ++j) {
        const int klocal = ((lane >> 4) << 3) + j;
        const int c = ks * 32 + klocal;
        dst[j] = f2b(w2[(size_t)m * OC + c]);
    }
}

// ---------------------------------------------------------------------------
// Fused kernel, N-tile = 64, 512 threads (8 waves), 4 blocks/CU (32 waves/CU).
// Conv wave tile M=96 x N=16 (wm=wid&1, wn=wid>>1 in 0..3).
// Logits: wave-half mf split (wid<4: mf0..4, wid>=4: mf4..8; mf4 duplicated).
// LDS (octet-major, union):
//   xl: [rp6][oct4][col64][8] = 24576 B (+halo 192 B)
//   yl: [coct24][ow64][8]     = 24576 B
//   p : [144][64] bf16 rotated = 18432 B
// Total ~26 KB => 6 by LDS, 4 by waves => 4 blocks/CU, grid 2048 = 2 rounds.
// ---------------------------------------------------------------------------
#define XL_MAIN (6 * 4 * 64 * 8)          // 12288 ushorts
#define UNION_USHORTS (XL_MAIN + 3 * 32)  // 12384 ushorts = 24768 B

__global__ __launch_bounds__(512, 8) void fused(
        const float* __restrict__ x, const ushort* __restrict__ apack,
        const ushort* __restrict__ w2p,
        const float* __restrict__ gamma, const float* __restrict__ beta,
        float* __restrict__ out) {
    __shared__ __align__(16) ushort smem[UNION_USHORTS];
    __shared__ float sc[OC], bi[OC];

    // bijective XCD swizzle (2048 % 8 == 0): each XCD gets a contiguous slab
    const int bid0 = blockIdx.x;
    const int bid = (bid0 & 7) * 256 + (bid0 >> 3);
    const int owt = bid & 3;
    const int oh = (bid >> 2) & 127;
    const int b = bid >> 9;
    const int ow0 = owt * 64;
    const int tid = threadIdx.x;
    const int wid = tid >> 6;       // 0..7
    const int wm = wid & 1;         // conv M half: oc base wm*96
    const int wn = wid >> 1;        // conv N quarter: ow base wn*16
    const int lane = tid & 63;
    const int r = lane & 15;
    const int q = lane >> 4;

    if (tid < OC) {
        const float bnr = 1.0f / sqrtf(1.0f + 1e-5f);
        sc[tid] = gamma[tid] * bnr;
        bi[tid] = beta[tid];
    }

    f32x4 cacc[6];
#pragma unroll
    for (int mf = 0; mf < 6; ++mf) cacc[mf] = (f32x4){0.f, 0.f, 0.f, 0.f};

    const size_t chs = (size_t)Hh * Ww;

    // ================= conv phase =================
    for (int chunk = 0; chunk < 3; ++chunk) {
        __syncthreads();
        const int icc = chunk * 32;
        // staging: 768 slots = (oct4, colp64, row3); each loads 8ch float2
#pragma unroll
        for (int it = 0; it < 2; ++it) {
            const int g3 = (it << 9) + tid;
            if (g3 < 768) {
                const int oct = g3 & 3;
                const int colp = (g3 >> 2) & 63;
                const int row = g3 >> 8;            // 0..2
                const int ih = 2 * oh - 1 + row;
                const int gcol = 2 * (ow0 + colp);
                float2 v[8];
                if (ih >= 0) {
                    const float* xp = x + ((size_t)(b * Cc + icc + (oct << 3)) * Hh + ih) * Ww + gcol;
#pragma unroll
                    for (int j = 0; j < 8; ++j)
                        v[j] = *reinterpret_cast<const float2*>(xp + (size_t)j * chs);
                } else {
#pragma unroll
                    for (int j = 0; j < 8; ++j) v[j] = make_float2(0.f, 0.f);
                }
                bf16x8 u0, u1;
#pragma unroll
                for (int j = 0; j < 8; ++j) {
                    u0[j] = (short)f2b(v[j].x);
                    u1[j] = (short)f2b(v[j].y);
                }
                *reinterpret_cast<bf16x8*>(smem + (((row * 2 + 0) * 4 + oct) * 64 + colp) * 8) = u0;
                *reinterpret_cast<bf16x8*>(smem + (((row * 2 + 1) * 4 + oct) * 64 + colp) * 8) = u1;
            }
        }
        if (tid < 12) {
            const int oct = tid & 3;
            const int row = tid >> 2;
            const int ih = 2 * oh - 1 + row;
            const int gcol = 2 * ow0 - 1;
            float v[8];
            if (ih >= 0 && gcol >= 0) {
                const float* xp = x + ((size_t)(b * Cc + icc + (oct << 3)) * Hh + ih) * Ww + gcol;
#pragma unroll
                for (int j = 0; j < 8; ++j) v[j] = xp[(size_t)j * chs];
            } else {
#pragma unroll
                for (int j = 0; j < 8; ++j) v[j] = 0.f;
            }
            bf16x8 u;
#pragma unroll
            for (int j = 0; j < 8; ++j) u[j] = (short)f2b(v[j]);
            *reinterpret_cast<bf16x8*>(smem + XL_MAIN + row * 32 + oct * 8) = u;
        }
        __syncthreads();

#pragma unroll
        for (int tap = 0; tap < 9; ++tap) {
            const int kh = tap / 3, kw = tap % 3;
            const int par = (kw == 1) ? 0 : 1;
            const int cb = (kw == 0) ? -1 : 0;
            const int k0 = chunk * 9 + tap;

            bf16x8 af[6];
            const ushort* ap = apack + (((size_t)(k0 * 12 + wm * 6) * 64) + lane) * 8;
#pragma unroll
            for (int mf = 0; mf < 6; ++mf)
                af[mf] = *reinterpret_cast<const bf16x8*>(ap + (size_t)mf * 64 * 8);

            const int colc = wn * 16 + r + cb;
            const ushort* src = (colc >= 0)
                ? smem + (((kh * 2 + par) * 4 + q) * 64 + colc) * 8
                : smem + XL_MAIN + kh * 32 + q * 8;
            const bf16x8 bfr = *reinterpret_cast<const bf16x8*>(src);
#pragma unroll
            for (int mf = 0; mf < 6; ++mf)
                cacc[mf] = __builtin_amdgcn_mfma_f32_16x16x32_bf16(
                    af[mf], bfr, cacc[mf], 0, 0, 0);
        }
    }

    // ====== epilogue: BN+LReLU -> yl[coct][ow][8] bf16 ======
    __syncthreads();
#pragma unroll
    for (int mf = 0; mf < 6; ++mf) {
        const int cbase = wm * 96 + mf * 16;
        const int coct = (cbase >> 3) + (q >> 1);
        const int ow = wn * 16 + r;
        ushort pk[4];
#pragma unroll
        for (int rr = 0; rr < 4; ++rr) {
            const int oc = cbase + q * 4 + rr;
            float v = cacc[mf][rr] * sc[oc] + bi[oc];
            v = (v >= 0.f) ? v : 0.1f * v;
            pk[rr] = f2b(v);
        }
        *reinterpret_cast<bf16x4*>(smem + (coct * 64 + ow) * 8 + (q & 1) * 4) =
            *reinterpret_cast<bf16x4*>(pk);
    }
    __syncthreads();

    // ============ logits MFMA: wave-half mf split ============
    const int hi = wid >> 2;         // 0: mf 0..4, 1: mf 4..8
    const int mfbase = hi * 4;
    f32x4 macc[5];
#pragma unroll
    for (int mf = 0; mf < 5; ++mf) macc[mf] = (f32x4){0.f, 0.f, 0.f, 0.f};

    const int owq = (wid & 3) * 16 + r;   // this lane's logits column (0..63)
#pragma unroll
    for (int ks = 0; ks < 6; ++ks) {
        bf16x8 af[5];
        const ushort* ap = w2p + (((size_t)(ks * 9 + mfbase) * 64) + lane) * 8;
#pragma unroll
        for (int mf = 0; mf < 5; ++mf)
            af[mf] = *reinterpret_cast<const bf16x8*>(ap + (size_t)mf * 64 * 8);
        const bf16x8 bfr = *reinterpret_cast<const bf16x8*>(smem + ((ks * 4 + q) * 64 + owq) * 8);
#pragma unroll
        for (int mf = 0; mf < 5; ++mf)
            macc[mf] = __builtin_amdgcn_mfma_f32_16x16x32_bf16(af[mf], bfr, macc[mf], 0, 0, 0);
    }
    __syncthreads();   // yl reads done; p overwrites

    // ===== in-register softmax -> p[144][64] (bf16, normalized, rotated) =====
    {
        const int col = (owq + q * 16) & 63;
#pragma unroll
        for (int gi = 0; gi < 2; ++gi) {
            const int gl = hi * 2 + gi;          // wave-half handles 2 group-slots
            const int g = q * 4 + gl;
            float pv[9];
            float mx = -1e30f;
#pragma unroll
            for (int k = 0; k < 9; ++k) {
                const int s = gl * 9 + k;
                pv[k] = macc[(s >> 2) - mfbase][s & 3];
                mx = fmaxf(mx, pv[k]);
            }
            float ssum = 0.f;
#pragma unroll
            for (int k = 0; k < 9; ++k) { pv[k] = __expf(pv[k] - mx); ssum += pv[k]; }
            const float inv = 1.f / ssum;
#pragma unroll
            for (int k = 0; k < 9; ++k)
                smem[(g * 9 + k) * 64 + col] = f2b(pv[k] * inv);
        }
    }
    __syncthreads();

    // ============ apply phase (coalesced) ============
    const int ih0 = 2 * oh - 1;
    const bool okh0 = (oh > 0);
#pragma unroll
    for (int it = 0; it < 2; ++it) {
        const int idx = (it << 9) + tid;
        const int g = idx >> 6;                 // 0..15, wave-uniform
        const int owl = idx & 63;
        const int owg = ow0 + owl;
        const int col = (owl + (g >> 2) * 16) & 63;

        float p[9];
#pragma unroll
        for (int k = 0; k < 9; ++k) p[k] = b2f(smem[(g * 9 + k) * 64 + col]);

        const int iw0 = 2 * owg - 1;
        const bool okw0 = (owg > 0);
#pragma unroll
        for (int i = 0; i < CPG; ++i) {
            const int cc = i * Gg + g;
            const float* xc = x + (size_t)(b * Cc + cc) * chs;
            float acc = 0.f;
#pragma unroll
            for (int kh = 0; kh < 3; ++kh) {
                if (kh == 0 && !okh0) continue;
                const float* rowp = xc + (size_t)(ih0 + kh) * Ww + iw0;
                const float v0 = okw0 ? rowp[0] : 0.f;
                const float2 v12 = *reinterpret_cast<const float2*>(rowp + 1);
                acc += p[kh * 3 + 0] * v0 + p[kh * 3 + 1] * v12.x
                     + p[kh * 3 + 2] * v12.y;
            }
            out[((size_t)(b * Cc + cc) * HO + oh) * WO + owg] = acc;
        }
    }
}

extern "C" void kernel_launch(void* const* d_in, const int* in_sizes, int n_in,
                              void* d_out, int out_size, void* d_ws, size_t ws_size,
                              hipStream_t stream) {
    const float* x     = (const float*)d_in[0];
    const float* w1    = (const float*)d_in[1];
    const float* gamma = (const float*)d_in[2];
    const float* beta  = (const float*)d_in[3];
    const float* w2    = (const float*)d_in[4];
    float* out = (float*)d_out;

    ushort* apack = (ushort*)d_ws;                           // 331,776 B
    ushort* w2p   = (ushort*)((char*)d_ws + 331776);         // + 55,296 B

    pack_w1<<<27 * 12, 64, 0, stream>>>(w1, apack);
    pack_w2<<<6 * 9, 64, 0, stream>>>(w2, w2p);
    fused<<<Bb * HO * 4, 512, 0, stream>>>(x, apack, w2p, gamma, beta, out);
}

// Round 11
// 233.961 us; speedup vs baseline: 1.0411x; 1.0411x over previous
//
#include <hip/hip_runtime.h>
#include <hip/hip_bf16.h>

#define Bb 4
#define Cc 96
#define Hh 256
#define Ww 512
#define OC 192
#define HO 128
#define WO 256
#define Gg 16
#define CPG 6

typedef __attribute__((ext_vector_type(4))) float f32x4;
typedef __attribute__((ext_vector_type(8))) short bf16x8;
typedef __attribute__((ext_vector_type(4))) short bf16x4;

static __device__ __forceinline__ ushort f2b(float f) {
    __hip_bfloat16 h = __float2bfloat16(f);
    return *reinterpret_cast<ushort*>(&h);
}
static __device__ __forceinline__ float b2f(ushort u) {
    unsigned int v = ((unsigned int)u) << 16;
    return __builtin_bit_cast(float, v);
}

// ---------------------------------------------------------------------------
// Pack w1, MFMA fragment order, klocal = q*8 + j (verified R7).
// ---------------------------------------------------------------------------
__global__ __launch_bounds__(64) void pack_w1(const float* __restrict__ w1,
                                              ushort* __restrict__ apack) {
    const int blk = blockIdx.x;      // 27*12
    const int k0 = blk / 12;
    const int mf = blk % 12;
    const int lane = threadIdx.x;
    const int m = mf * 16 + (lane & 15);
    const int chunk = k0 / 9;
    const int tap = k0 % 9;
    ushort* dst = apack + (((size_t)(k0 * 12 + mf) * 64) + lane) * 8;
#pragma unroll
    for (int j = 0; j < 8; ++j) {
        const int klocal = ((lane >> 4) << 3) + j;
        const int ic = chunk * 32 + klocal;
        dst[j] = f2b(w1[(size_t)(m * Cc + ic) * 9 + tap]);
    }
}

// ---------------------------------------------------------------------------
// Pack w2, softmax-group row permutation (verified R5) + klocal = q*8+j (R7).
// ---------------------------------------------------------------------------
__global__ __launch_bounds__(64) void pack_w2(const float* __restrict__ w2,
                                              ushort* __restrict__ w2p) {
    const int blk = blockIdx.x;      // 6*9
    const int ks = blk / 9;
    const int mf = blk % 9;
    const int lane = threadIdx.x;
    const int X = lane & 15;
    const int qq = X >> 2;
    const int rr = X & 3;
    const int s = mf * 4 + rr;
    const int g = qq * 4 + s / 9;
    const int k = s % 9;
    const int m = g * 9 + k;
    ushort* dst = w2p + (((size_t)(ks * 9 + mf) * 64) + lane) * 8;
#pragma unroll
    for (int j = 0; j < 8; ++j) {
        const int klocal = ((lane >> 4) << 3) + j;
        const int c = ks * 32 + klocal;
        dst[j] = f2b(w2[(size_t)m * OC + c]);
    }
}

// ---------------------------------------------------------------------------
// Fused kernel, N-tile = 64, 512 threads (8 waves).
// __launch_bounds__(512,4): VGPR cap 128, natural use ~64 -> no spills;
// runtime occupancy = 4 blocks/CU (32 waves/CU, wave-capacity max).
// Conv wave tile M=96 x N=16; logits wave-half mf split (mf4 duplicated).
// LDS (octet-major, union): xl 24576 B (+halo) | yl 24576 B | p 18432 B.
// Grid 2048 (XCD-swizzled) = 2 exact rounds of 4/CU.
// ---------------------------------------------------------------------------
#define XL_MAIN (6 * 4 * 64 * 8)          // 12288 ushorts
#define UNION_USHORTS (XL_MAIN + 3 * 32)  // 12384 ushorts = 24768 B

__global__ __launch_bounds__(512, 4) void fused(
        const float* __restrict__ x, const ushort* __restrict__ apack,
        const ushort* __restrict__ w2p,
        const float* __restrict__ gamma, const float* __restrict__ beta,
        float* __restrict__ out) {
    __shared__ __align__(16) ushort smem[UNION_USHORTS];
    __shared__ float sc[OC], bi[OC];

    // bijective XCD swizzle (2048 % 8 == 0): each XCD gets a contiguous slab
    const int bid0 = blockIdx.x;
    const int bid = (bid0 & 7) * 256 + (bid0 >> 3);
    const int owt = bid & 3;
    const int oh = (bid >> 2) & 127;
    const int b = bid >> 9;
    const int ow0 = owt * 64;
    const int tid = threadIdx.x;
    const int wid = tid >> 6;       // 0..7
    const int wm = wid & 1;         // conv M half: oc base wm*96
    const int wn = wid >> 1;        // conv N quarter: ow base wn*16
    const int lane = tid & 63;
    const int r = lane & 15;
    const int q = lane >> 4;

    if (tid < OC) {
        const float bnr = 1.0f / sqrtf(1.0f + 1e-5f);
        sc[tid] = gamma[tid] * bnr;
        bi[tid] = beta[tid];
    }

    f32x4 cacc[6];
#pragma unroll
    for (int mf = 0; mf < 6; ++mf) cacc[mf] = (f32x4){0.f, 0.f, 0.f, 0.f};

    const size_t chs = (size_t)Hh * Ww;

    // ================= conv phase =================
    for (int chunk = 0; chunk < 3; ++chunk) {
        __syncthreads();
        const int icc = chunk * 32;
        // staging: 768 slots = (oct4, colp64, row3); each loads 8ch float2
#pragma unroll
        for (int it = 0; it < 2; ++it) {
            const int g3 = (it << 9) + tid;
            if (g3 < 768) {
                const int oct = g3 & 3;
                const int colp = (g3 >> 2) & 63;
                const int row = g3 >> 8;            // 0..2
                const int ih = 2 * oh - 1 + row;
                const int gcol = 2 * (ow0 + colp);
                float2 v[8];
                if (ih >= 0) {
                    const float* xp = x + ((size_t)(b * Cc + icc + (oct << 3)) * Hh + ih) * Ww + gcol;
#pragma unroll
                    for (int j = 0; j < 8; ++j)
                        v[j] = *reinterpret_cast<const float2*>(xp + (size_t)j * chs);
                } else {
#pragma unroll
                    for (int j = 0; j < 8; ++j) v[j] = make_float2(0.f, 0.f);
                }
                bf16x8 u0, u1;
#pragma unroll
                for (int j = 0; j < 8; ++j) {
                    u0[j] = (short)f2b(v[j].x);
                    u1[j] = (short)f2b(v[j].y);
                }
                *reinterpret_cast<bf16x8*>(smem + (((row * 2 + 0) * 4 + oct) * 64 + colp) * 8) = u0;
                *reinterpret_cast<bf16x8*>(smem + (((row * 2 + 1) * 4 + oct) * 64 + colp) * 8) = u1;
            }
        }
        if (tid < 12) {
            const int oct = tid & 3;
            const int row = tid >> 2;
            const int ih = 2 * oh - 1 + row;
            const int gcol = 2 * ow0 - 1;
            float v[8];
            if (ih >= 0 && gcol >= 0) {
                const float* xp = x + ((size_t)(b * Cc + icc + (oct << 3)) * Hh + ih) * Ww + gcol;
#pragma unroll
                for (int j = 0; j < 8; ++j) v[j] = xp[(size_t)j * chs];
            } else {
#pragma unroll
                for (int j = 0; j < 8; ++j) v[j] = 0.f;
            }
            bf16x8 u;
#pragma unroll
            for (int j = 0; j < 8; ++j) u[j] = (short)f2b(v[j]);
            *reinterpret_cast<bf16x8*>(smem + XL_MAIN + row * 32 + oct * 8) = u;
        }
        __syncthreads();

#pragma unroll
        for (int tap = 0; tap < 9; ++tap) {
            const int kh = tap / 3, kw = tap % 3;
            const int par = (kw == 1) ? 0 : 1;
            const int cb = (kw == 0) ? -1 : 0;
            const int k0 = chunk * 9 + tap;

            bf16x8 af[6];
            const ushort* ap = apack + (((size_t)(k0 * 12 + wm * 6) * 64) + lane) * 8;
#pragma unroll
            for (int mf = 0; mf < 6; ++mf)
                af[mf] = *reinterpret_cast<const bf16x8*>(ap + (size_t)mf * 64 * 8);

            const int colc = wn * 16 + r + cb;
            const ushort* src = (colc >= 0)
                ? smem + (((kh * 2 + par) * 4 + q) * 64 + colc) * 8
                : smem + XL_MAIN + kh * 32 + q * 8;
            const bf16x8 bfr = *reinterpret_cast<const bf16x8*>(src);
#pragma unroll
            for (int mf = 0; mf < 6; ++mf)
                cacc[mf] = __builtin_amdgcn_mfma_f32_16x16x32_bf16(
                    af[mf], bfr, cacc[mf], 0, 0, 0);
        }
    }

    // ====== epilogue: BN+LReLU -> yl[coct][ow][8] bf16 ======
    __syncthreads();
#pragma unroll
    for (int mf = 0; mf < 6; ++mf) {
        const int cbase = wm * 96 + mf * 16;
        const int coct = (cbase >> 3) + (q >> 1);
        const int ow = wn * 16 + r;
        ushort pk[4];
#pragma unroll
        for (int rr = 0; rr < 4; ++rr) {
            const int oc = cbase + q * 4 + rr;
            float v = cacc[mf][rr] * sc[oc] + bi[oc];
            v = (v >= 0.f) ? v : 0.1f * v;
            pk[rr] = f2b(v);
        }
        *reinterpret_cast<bf16x4*>(smem + (coct * 64 + ow) * 8 + (q & 1) * 4) =
            *reinterpret_cast<bf16x4*>(pk);
    }
    __syncthreads();

    // ============ logits MFMA: wave-half mf split ============
    const int hi = wid >> 2;         // 0: mf 0..4, 1: mf 4..8
    const int mfbase = hi * 4;
    f32x4 macc[5];
#pragma unroll
    for (int mf = 0; mf < 5; ++mf) macc[mf] = (f32x4){0.f, 0.f, 0.f, 0.f};

    const int owq = (wid & 3) * 16 + r;   // this lane's logits column (0..63)
#pragma unroll
    for (int ks = 0; ks < 6; ++ks) {
        bf16x8 af[5];
        const ushort* ap = w2p + (((size_t)(ks * 9 + mfbase) * 64) + lane) * 8;
#pragma unroll
        for (int mf = 0; mf < 5; ++mf)
            af[mf] = *reinterpret_cast<const bf16x8*>(ap + (size_t)mf * 64 * 8);
        const bf16x8 bfr = *reinterpret_cast<const bf16x8*>(smem + ((ks * 4 + q) * 64 + owq) * 8);
#pragma unroll
        for (int mf = 0; mf < 5; ++mf)
            macc[mf] = __builtin_amdgcn_mfma_f32_16x16x32_bf16(af[mf], bfr, macc[mf], 0, 0, 0);
    }
    __syncthreads();   // yl reads done; p overwrites

    // ===== in-register softmax -> p[144][64] (bf16, normalized, rotated) =====
    {
        const int col = (owq + q * 16) & 63;
#pragma unroll
        for (int gi = 0; gi < 2; ++gi) {
            const int gl = hi * 2 + gi;          // wave-half handles 2 group-slots
            const int g = q * 4 + gl;
            float pv[9];
            float mx = -1e30f;
#pragma unroll
            for (int k = 0; k < 9; ++k) {
                const int s = gl * 9 + k;
                pv[k] = macc[(s >> 2) - mfbase][s & 3];
                mx = fmaxf(mx, pv[k]);
            }
            float ssum = 0.f;
#pragma unroll
            for (int k = 0; k < 9; ++k) { pv[k] = __expf(pv[k] - mx); ssum += pv[k]; }
            const float inv = 1.f / ssum;
#pragma unroll
            for (int k = 0; k < 9; ++k)
                smem[(g * 9 + k) * 64 + col] = f2b(pv[k] * inv);
        }
    }
    __syncthreads();

    // ============ apply phase (coalesced) ============
    const int ih0 = 2 * oh - 1;
    const bool okh0 = (oh > 0);
#pragma unroll
    for (int it = 0; it < 2; ++it) {
        const int idx = (it << 9) + tid;
        const int g = idx >> 6;                 // 0..15, wave-uniform
        const int owl = idx & 63;
        const int owg = ow0 + owl;
        const int col = (owl + (g >> 2) * 16) & 63;

        float p[9];
#pragma unroll
        for (int k = 0; k < 9; ++k) p[k] = b2f(smem[(g * 9 + k) * 64 + col]);

        const int iw0 = 2 * owg - 1;
        const bool okw0 = (owg > 0);
#pragma unroll
        for (int i = 0; i < CPG; ++i) {
            const int cc = i * Gg + g;
            const float* xc = x + (size_t)(b * Cc + cc) * chs;
            float acc = 0.f;
#pragma unroll
            for (int kh = 0; kh < 3; ++kh) {
                if (kh == 0 && !okh0) continue;
                const float* rowp = xc + (size_t)(ih0 + kh) * Ww + iw0;
                const float v0 = okw0 ? rowp[0] : 0.f;
                const float2 v12 = *reinterpret_cast<const float2*>(rowp + 1);
                acc += p[kh * 3 + 0] * v0 + p[kh * 3 + 1] * v12.x
                     + p[kh * 3 + 2] * v12.y;
            }
            out[((size_t)(b * Cc + cc) * HO + oh) * WO + owg] = acc;
        }
    }
}

extern "C" void kernel_launch(void* const* d_in, const int* in_sizes, int n_in,
                              void* d_out, int out_size, void* d_ws, size_t ws_size,
                              hipStream_t stream) {
    const float* x     = (const float*)d_in[0];
    const float* w1    = (const float*)d_in[1];
    const float* gamma = (const float*)d_in[2];
    const float* beta  = (const float*)d_in[3];
    const float* w2    = (const float*)d_in[4];
    float* out = (float*)d_out;

    ushort* apack = (ushort*)d_ws;                           // 331,776 B
    ushort* w2p   = (ushort*)((char*)d_ws + 331776);         // + 55,296 B

    pack_w1<<<27 * 12, 64, 0, stream>>>(w1, apack);
    pack_w2<<<6 * 9, 64, 0, stream>>>(w2, w2p);
    fused<<<Bb * HO * 4, 512, 0, stream>>>(x, apack, w2p, gamma, beta, out);
}

// Round 12
// 215.016 us; speedup vs baseline: 1.1328x; 1.0881x over previous
//
#include <hip/hip_runtime.h>
#include <hip/hip_bf16.h>

#define Bb 4
#define Cc 96
#define Hh 256
#define Ww 512
#define OC 192
#define HO 128
#define WO 256
#define Gg 16
#define CPG 6

typedef __attribute__((ext_vector_type(4))) float f32x4;
typedef __attribute__((ext_vector_type(8))) short bf16x8;
typedef __attribute__((ext_vector_type(4))) short bf16x4;

static __device__ __forceinline__ ushort f2b(float f) {
    __hip_bfloat16 h = __float2bfloat16(f);
    return *reinterpret_cast<ushort*>(&h);
}
static __device__ __forceinline__ float b2f(ushort u) {
    unsigned int v = ((unsigned int)u) << 16;
    return __builtin_bit_cast(float, v);
}

// ---------------------------------------------------------------------------
// Pack w1, MFMA fragment order, klocal = q*8 + j (verified R7).
// ---------------------------------------------------------------------------
__global__ __launch_bounds__(64) void pack_w1(const float* __restrict__ w1,
                                              ushort* __restrict__ apack) {
    const int blk = blockIdx.x;      // 27*12
    const int k0 = blk / 12;
    const int mf = blk % 12;
    const int lane = threadIdx.x;
    const int m = mf * 16 + (lane & 15);
    const int chunk = k0 / 9;
    const int tap = k0 % 9;
    ushort* dst = apack + (((size_t)(k0 * 12 + mf) * 64) + lane) * 8;
#pragma unroll
    for (int j = 0; j < 8; ++j) {
        const int klocal = ((lane >> 4) << 3) + j;
        const int ic = chunk * 32 + klocal;
        dst[j] = f2b(w1[(size_t)(m * Cc + ic) * 9 + tap]);
    }
}

// ---------------------------------------------------------------------------
// Pack w2, softmax-group row permutation (verified R5) + klocal = q*8+j (R7).
// ---------------------------------------------------------------------------
__global__ __launch_bounds__(64) void pack_w2(const float* __restrict__ w2,
                                              ushort* __restrict__ w2p) {
    const int blk = blockIdx.x;      // 6*9
    const int ks = blk / 9;
    const int mf = blk % 9;
    const int lane = threadIdx.x;
    const int X = lane & 15;
    const int qq = X >> 2;
    const int rr = X & 3;
    const int s = mf * 4 + rr;
    const int g = qq * 4 + s / 9;
    const int k = s % 9;
    const int m = g * 9 + k;
    ushort* dst = w2p + (((size_t)(ks * 9 + mf) * 64) + lane) * 8;
#pragma unroll
    for (int j = 0; j < 8; ++j) {
        const int klocal = ((lane >> 4) << 3) + j;
        const int c = ks * 32 + klocal;
        dst[j] = f2b(w2[(size_t)m * OC + c]);
    }
}

// ---------------------------------------------------------------------------
// Softmax extraction with ALL-STATIC macc indices (rule #20: runtime index
// into a register array goes to scratch). MB = wave-half (0: mf0..4, 1: mf4..8).
// ---------------------------------------------------------------------------
template<int MB>
static __device__ __forceinline__ void softmax_to_lds(
        const f32x4 (&macc)[5], ushort* __restrict__ smem, int q, int col) {
#pragma unroll
    for (int gi = 0; gi < 2; ++gi) {
        const int gl = MB * 2 + gi;              // compile-time after unroll
        const int g = q * 4 + gl;
        float pv[9];
        float mx = -1e30f;
#pragma unroll
        for (int k = 0; k < 9; ++k) {
            const int s = gl * 9 + k;            // compile-time
            pv[k] = macc[(s >> 2) - MB * 4][s & 3];  // static indices
            mx = fmaxf(mx, pv[k]);
        }
        float ssum = 0.f;
#pragma unroll
        for (int k = 0; k < 9; ++k) { pv[k] = __expf(pv[k] - mx); ssum += pv[k]; }
        const float inv = 1.f / ssum;
#pragma unroll
        for (int k = 0; k < 9; ++k)
            smem[(g * 9 + k) * 64 + col] = f2b(pv[k] * inv);
    }
}

// ---------------------------------------------------------------------------
// Fused kernel, N-tile = 64, 512 threads (8 waves), __launch_bounds__(512,4).
// Conv wave tile M=96 x N=16; logits wave-half mf split (mf4 duplicated).
// LDS (octet-major, union): xl 24576 B (+halo) | yl 24576 B | p 18432 B.
// Grid 2048 (XCD-swizzled) = 2 exact rounds of 4/CU.
// ---------------------------------------------------------------------------
#define XL_MAIN (6 * 4 * 64 * 8)          // 12288 ushorts
#define UNION_USHORTS (XL_MAIN + 3 * 32)  // 12384 ushorts = 24768 B

__global__ __launch_bounds__(512, 4) void fused(
        const float* __restrict__ x, const ushort* __restrict__ apack,
        const ushort* __restrict__ w2p,
        const float* __restrict__ gamma, const float* __restrict__ beta,
        float* __restrict__ out) {
    __shared__ __align__(16) ushort smem[UNION_USHORTS];
    __shared__ float sc[OC], bi[OC];

    // bijective XCD swizzle (2048 % 8 == 0): each XCD gets a contiguous slab
    const int bid0 = blockIdx.x;
    const int bid = (bid0 & 7) * 256 + (bid0 >> 3);
    const int owt = bid & 3;
    const int oh = (bid >> 2) & 127;
    const int b = bid >> 9;
    const int ow0 = owt * 64;
    const int tid = threadIdx.x;
    const int wid = tid >> 6;       // 0..7
    const int wm = wid & 1;         // conv M half: oc base wm*96
    const int wn = wid >> 1;        // conv N quarter: ow base wn*16
    const int lane = tid & 63;
    const int r = lane & 15;
    const int q = lane >> 4;

    if (tid < OC) {
        const float bnr = 1.0f / sqrtf(1.0f + 1e-5f);
        sc[tid] = gamma[tid] * bnr;
        bi[tid] = beta[tid];
    }

    f32x4 cacc[6];
#pragma unroll
    for (int mf = 0; mf < 6; ++mf) cacc[mf] = (f32x4){0.f, 0.f, 0.f, 0.f};

    const size_t chs = (size_t)Hh * Ww;

    // ================= conv phase =================
    for (int chunk = 0; chunk < 3; ++chunk) {
        __syncthreads();
        const int icc = chunk * 32;
        // staging: 768 slots = (oct4, colp64, row3); each loads 8ch float2
#pragma unroll
        for (int it = 0; it < 2; ++it) {
            const int g3 = (it << 9) + tid;
            if (g3 < 768) {
                const int oct = g3 & 3;
                const int colp = (g3 >> 2) & 63;
                const int row = g3 >> 8;            // 0..2
                const int ih = 2 * oh - 1 + row;
                const int gcol = 2 * (ow0 + colp);
                float2 v[8];
                if (ih >= 0) {
                    const float* xp = x + ((size_t)(b * Cc + icc + (oct << 3)) * Hh + ih) * Ww + gcol;
#pragma unroll
                    for (int j = 0; j < 8; ++j)
                        v[j] = *reinterpret_cast<const float2*>(xp + (size_t)j * chs);
                } else {
#pragma unroll
                    for (int j = 0; j < 8; ++j) v[j] = make_float2(0.f, 0.f);
                }
                bf16x8 u0, u1;
#pragma unroll
                for (int j = 0; j < 8; ++j) {
                    u0[j] = (short)f2b(v[j].x);
                    u1[j] = (short)f2b(v[j].y);
                }
                *reinterpret_cast<bf16x8*>(smem + (((row * 2 + 0) * 4 + oct) * 64 + colp) * 8) = u0;
                *reinterpret_cast<bf16x8*>(smem + (((row * 2 + 1) * 4 + oct) * 64 + colp) * 8) = u1;
            }
        }
        if (tid < 12) {
            const int oct = tid & 3;
            const int row = tid >> 2;
            const int ih = 2 * oh - 1 + row;
            const int gcol = 2 * ow0 - 1;
            float v[8];
            if (ih >= 0 && gcol >= 0) {
                const float* xp = x + ((size_t)(b * Cc + icc + (oct << 3)) * Hh + ih) * Ww + gcol;
#pragma unroll
                for (int j = 0; j < 8; ++j) v[j] = xp[(size_t)j * chs];
            } else {
#pragma unroll
                for (int j = 0; j < 8; ++j) v[j] = 0.f;
            }
            bf16x8 u;
#pragma unroll
            for (int j = 0; j < 8; ++j) u[j] = (short)f2b(v[j]);
            *reinterpret_cast<bf16x8*>(smem + XL_MAIN + row * 32 + oct * 8) = u;
        }
        __syncthreads();

#pragma unroll
        for (int tap = 0; tap < 9; ++tap) {
            const int kh = tap / 3, kw = tap % 3;
            const int par = (kw == 1) ? 0 : 1;
            const int cb = (kw == 0) ? -1 : 0;
            const int k0 = chunk * 9 + tap;

            bf16x8 af[6];
            const ushort* ap = apack + (((size_t)(k0 * 12 + wm * 6) * 64) + lane) * 8;
#pragma unroll
            for (int mf = 0; mf < 6; ++mf)
                af[mf] = *reinterpret_cast<const bf16x8*>(ap + (size_t)mf * 64 * 8);

            const int colc = wn * 16 + r + cb;
            const ushort* src = (colc >= 0)
                ? smem + (((kh * 2 + par) * 4 + q) * 64 + colc) * 8
                : smem + XL_MAIN + kh * 32 + q * 8;
            const bf16x8 bfr = *reinterpret_cast<const bf16x8*>(src);
#pragma unroll
            for (int mf = 0; mf < 6; ++mf)
                cacc[mf] = __builtin_amdgcn_mfma_f32_16x16x32_bf16(
                    af[mf], bfr, cacc[mf], 0, 0, 0);
        }
    }

    // ====== epilogue: BN+LReLU -> yl[coct][ow][8] bf16 ======
    __syncthreads();
#pragma unroll
    for (int mf = 0; mf < 6; ++mf) {
        const int cbase = wm * 96 + mf * 16;
        const int coct = (cbase >> 3) + (q >> 1);
        const int ow = wn * 16 + r;
        ushort pk[4];
#pragma unroll
        for (int rr = 0; rr < 4; ++rr) {
            const int oc = cbase + q * 4 + rr;
            float v = cacc[mf][rr] * sc[oc] + bi[oc];
            v = (v >= 0.f) ? v : 0.1f * v;
            pk[rr] = f2b(v);
        }
        *reinterpret_cast<bf16x4*>(smem + (coct * 64 + ow) * 8 + (q & 1) * 4) =
            *reinterpret_cast<bf16x4*>(pk);
    }
    __syncthreads();

    // ============ logits MFMA: wave-half mf split ============
    const int hi = wid >> 2;         // 0: mf 0..4, 1: mf 4..8
    const int mfbase = hi * 4;
    f32x4 macc[5];
#pragma unroll
    for (int mf = 0; mf < 5; ++mf) macc[mf] = (f32x4){0.f, 0.f, 0.f, 0.f};

    const int owq = (wid & 3) * 16 + r;   // this lane's logits column (0..63)
#pragma unroll
    for (int ks = 0; ks < 6; ++ks) {
        bf16x8 af[5];
        const ushort* ap = w2p + (((size_t)(ks * 9 + mfbase) * 64) + lane) * 8;
#pragma unroll
        for (int mf = 0; mf < 5; ++mf)
            af[mf] = *reinterpret_cast<const bf16x8*>(ap + (size_t)mf * 64 * 8);
        const bf16x8 bfr = *reinterpret_cast<const bf16x8*>(smem + ((ks * 4 + q) * 64 + owq) * 8);
#pragma unroll
        for (int mf = 0; mf < 5; ++mf)
            macc[mf] = __builtin_amdgcn_mfma_f32_16x16x32_bf16(af[mf], bfr, macc[mf], 0, 0, 0);
    }
    __syncthreads();   // yl reads done; p overwrites

    // ===== in-register softmax -> p[144][64]; static indices via template =====
    {
        const int col = (owq + q * 16) & 63;
        if (hi == 0) softmax_to_lds<0>(macc, smem, q, col);
        else         softmax_to_lds<1>(macc, smem, q, col);
    }
    __syncthreads();

    // ============ apply phase (coalesced) ============
    const int ih0 = 2 * oh - 1;
    const bool okh0 = (oh > 0);
#pragma unroll
    for (int it = 0; it < 2; ++it) {
        const int idx = (it << 9) + tid;
        const int g = idx >> 6;                 // 0..15, wave-uniform
        const int owl = idx & 63;
        const int owg = ow0 + owl;
        const int col = (owl + (g >> 2) * 16) & 63;

        float p[9];
#pragma unroll
        for (int k = 0; k < 9; ++k) p[k] = b2f(smem[(g * 9 + k) * 64 + col]);

        const int iw0 = 2 * owg - 1;
        const bool okw0 = (owg > 0);
#pragma unroll
        for (int i = 0; i < CPG; ++i) {
            const int cc = i * Gg + g;
            const float* xc = x + (size_t)(b * Cc + cc) * chs;
            float acc = 0.f;
#pragma unroll
            for (int kh = 0; kh < 3; ++kh) {
                if (kh == 0 && !okh0) continue;
                const float* rowp = xc + (size_t)(ih0 + kh) * Ww + iw0;
                const float v0 = okw0 ? rowp[0] : 0.f;
                const float2 v12 = *reinterpret_cast<const float2*>(rowp + 1);
                acc += p[kh * 3 + 0] * v0 + p[kh * 3 + 1] * v12.x
                     + p[kh * 3 + 2] * v12.y;
            }
            out[((size_t)(b * Cc + cc) * HO + oh) * WO + owg] = acc;
        }
    }
}

extern "C" void kernel_launch(void* const* d_in, const int* in_sizes, int n_in,
                              void* d_out, int out_size, void* d_ws, size_t ws_size,
                              hipStream_t stream) {
    const float* x     = (const float*)d_in[0];
    const float* w1    = (const float*)d_in[1];
    const float* gamma = (const float*)d_in[2];
    const float* beta  = (const float*)d_in[3];
    const float* w2    = (const float*)d_in[4];
    float* out = (float*)d_out;

    ushort* apack = (ushort*)d_ws;                           // 331,776 B
    ushort* w2p   = (ushort*)((char*)d_ws + 331776);         // + 55,296 B

    pack_w1<<<27 * 12, 64, 0, stream>>>(w1, apack);
    pack_w2<<<6 * 9, 64, 0, stream>>>(w2, w2p);
    fused<<<Bb * HO * 4, 512, 0, stream>>>(x, apack, w2p, gamma, beta, out);
}

// Round 13
// 213.146 us; speedup vs baseline: 1.1428x; 1.0088x over previous
//
#include <hip/hip_runtime.h>
#include <hip/hip_bf16.h>

#define Bb 4
#define Cc 96
#define Hh 256
#define Ww 512
#define OC 192
#define HO 128
#define WO 256
#define Gg 16
#define CPG 6

typedef __attribute__((ext_vector_type(4))) float f32x4;
typedef __attribute__((ext_vector_type(8))) short bf16x8;
typedef __attribute__((ext_vector_type(4))) short bf16x4;

static __device__ __forceinline__ ushort f2b(float f) {
    __hip_bfloat16 h = __float2bfloat16(f);
    return *reinterpret_cast<ushort*>(&h);
}
static __device__ __forceinline__ float b2f(ushort u) {
    unsigned int v = ((unsigned int)u) << 16;
    return __builtin_bit_cast(float, v);
}

// ---------------------------------------------------------------------------
// Pack w1, MFMA fragment order, klocal = q*8 + j (verified R7).
// ---------------------------------------------------------------------------
__global__ __launch_bounds__(64) void pack_w1(const float* __restrict__ w1,
                                              ushort* __restrict__ apack) {
    const int blk = blockIdx.x;      // 27*12
    const int k0 = blk / 12;
    const int mf = blk % 12;
    const int lane = threadIdx.x;
    const int m = mf * 16 + (lane & 15);
    const int chunk = k0 / 9;
    const int tap = k0 % 9;
    ushort* dst = apack + (((size_t)(k0 * 12 + mf) * 64) + lane) * 8;
#pragma unroll
    for (int j = 0; j < 8; ++j) {
        const int klocal = ((lane >> 4) << 3) + j;
        const int ic = chunk * 32 + klocal;
        dst[j] = f2b(w1[(size_t)(m * Cc + ic) * 9 + tap]);
    }
}

// ---------------------------------------------------------------------------
// Pack w2, softmax-group row permutation (verified R5) + klocal = q*8+j (R7).
// ---------------------------------------------------------------------------
__global__ __launch_bounds__(64) void pack_w2(const float* __restrict__ w2,
                                              ushort* __restrict__ w2p) {
    const int blk = blockIdx.x;      // 6*9
    const int ks = blk / 9;
    const int mf = blk % 9;
    const int lane = threadIdx.x;
    const int X = lane & 15;
    const int qq = X >> 2;
    const int rr = X & 3;
    const int s = mf * 4 + rr;
    const int g = qq * 4 + s / 9;
    const int k = s % 9;
    const int m = g * 9 + k;
    ushort* dst = w2p + (((size_t)(ks * 9 + mf) * 64) + lane) * 8;
#pragma unroll
    for (int j = 0; j < 8; ++j) {
        const int klocal = ((lane >> 4) << 3) + j;
        const int c = ks * 32 + klocal;
        dst[j] = f2b(w2[(size_t)m * OC + c]);
    }
}

// ---------------------------------------------------------------------------
// Softmax extraction with ALL-STATIC macc indices (rule #20). MB = wave-half.
// ---------------------------------------------------------------------------
template<int MB>
static __device__ __forceinline__ void softmax_to_lds(
        const f32x4 (&macc)[5], ushort* __restrict__ smem, int q, int col) {
#pragma unroll
    for (int gi = 0; gi < 2; ++gi) {
        const int gl = MB * 2 + gi;              // compile-time after unroll
        const int g = q * 4 + gl;
        float pv[9];
        float mx = -1e30f;
#pragma unroll
        for (int k = 0; k < 9; ++k) {
            const int s = gl * 9 + k;            // compile-time
            pv[k] = macc[(s >> 2) - MB * 4][s & 3];  // static indices
            mx = fmaxf(mx, pv[k]);
        }
        float ssum = 0.f;
#pragma unroll
        for (int k = 0; k < 9; ++k) { pv[k] = __expf(pv[k] - mx); ssum += pv[k]; }
        const float inv = 1.f / ssum;
#pragma unroll
        for (int k = 0; k < 9; ++k)
            smem[(g * 9 + k) * 64 + col] = f2b(pv[k] * inv);
    }
}

// ---------------------------------------------------------------------------
// Fused kernel, N-tile = 64, 512 threads (8 waves).
// __launch_bounds__(512) ONLY (no waves-per-eu arg): R9-R12 showed the 2nd
// arg clamps effective runtime residency (w=4 -> 44% occ) and small values
// force spill-caps (w=8 -> 32 VGPR). Natural VGPR ~56 allows 8 waves/SIMD.
// LDS (octet-major, union): xl 24576 B (+halo) | yl 24576 B | p 18432 B.
// Grid 2048 (XCD-swizzled) = 2 exact rounds of 4/CU.
// ---------------------------------------------------------------------------
#define XL_MAIN (6 * 4 * 64 * 8)          // 12288 ushorts
#define UNION_USHORTS (XL_MAIN + 3 * 32)  // 12384 ushorts = 24768 B

__global__ __launch_bounds__(512) void fused(
        const float* __restrict__ x, const ushort* __restrict__ apack,
        const ushort* __restrict__ w2p,
        const float* __restrict__ gamma, const float* __restrict__ beta,
        float* __restrict__ out) {
    __shared__ __align__(16) ushort smem[UNION_USHORTS];
    __shared__ float sc[OC], bi[OC];

    // bijective XCD swizzle (2048 % 8 == 0): each XCD gets a contiguous slab
    const int bid0 = blockIdx.x;
    const int bid = (bid0 & 7) * 256 + (bid0 >> 3);
    const int owt = bid & 3;
    const int oh = (bid >> 2) & 127;
    const int b = bid >> 9;
    const int ow0 = owt * 64;
    const int tid = threadIdx.x;
    const int wid = tid >> 6;       // 0..7
    const int wm = wid & 1;         // conv M half: oc base wm*96
    const int wn = wid >> 1;        // conv N quarter: ow base wn*16
    const int lane = tid & 63;
    const int r = lane & 15;
    const int q = lane >> 4;

    if (tid < OC) {
        const float bnr = 1.0f / sqrtf(1.0f + 1e-5f);
        sc[tid] = gamma[tid] * bnr;
        bi[tid] = beta[tid];
    }

    f32x4 cacc[6];
#pragma unroll
    for (int mf = 0; mf < 6; ++mf) cacc[mf] = (f32x4){0.f, 0.f, 0.f, 0.f};

    const size_t chs = (size_t)Hh * Ww;

    // ================= conv phase =================
    for (int chunk = 0; chunk < 3; ++chunk) {
        __syncthreads();
        const int icc = chunk * 32;
        // staging: 768 slots = (oct4, colp64, row3); each loads 8ch float2
#pragma unroll
        for (int it = 0; it < 2; ++it) {
            const int g3 = (it << 9) + tid;
            if (g3 < 768) {
                const int oct = g3 & 3;
                const int colp = (g3 >> 2) & 63;
                const int row = g3 >> 8;            // 0..2
                const int ih = 2 * oh - 1 + row;
                const int gcol = 2 * (ow0 + colp);
                float2 v[8];
                if (ih >= 0) {
                    const float* xp = x + ((size_t)(b * Cc + icc + (oct << 3)) * Hh + ih) * Ww + gcol;
#pragma unroll
                    for (int j = 0; j < 8; ++j)
                        v[j] = *reinterpret_cast<const float2*>(xp + (size_t)j * chs);
                } else {
#pragma unroll
                    for (int j = 0; j < 8; ++j) v[j] = make_float2(0.f, 0.f);
                }
                bf16x8 u0, u1;
#pragma unroll
                for (int j = 0; j < 8; ++j) {
                    u0[j] = (short)f2b(v[j].x);
                    u1[j] = (short)f2b(v[j].y);
                }
                *reinterpret_cast<bf16x8*>(smem + (((row * 2 + 0) * 4 + oct) * 64 + colp) * 8) = u0;
                *reinterpret_cast<bf16x8*>(smem + (((row * 2 + 1) * 4 + oct) * 64 + colp) * 8) = u1;
            }
        }
        if (tid < 12) {
            const int oct = tid & 3;
            const int row = tid >> 2;
            const int ih = 2 * oh - 1 + row;
            const int gcol = 2 * ow0 - 1;
            float v[8];
            if (ih >= 0 && gcol >= 0) {
                const float* xp = x + ((size_t)(b * Cc + icc + (oct << 3)) * Hh + ih) * Ww + gcol;
#pragma unroll
                for (int j = 0; j < 8; ++j) v[j] = xp[(size_t)j * chs];
            } else {
#pragma unroll
                for (int j = 0; j < 8; ++j) v[j] = 0.f;
            }
            bf16x8 u;
#pragma unroll
            for (int j = 0; j < 8; ++j) u[j] = (short)f2b(v[j]);
            *reinterpret_cast<bf16x8*>(smem + XL_MAIN + row * 32 + oct * 8) = u;
        }
        __syncthreads();

#pragma unroll
        for (int tap = 0; tap < 9; ++tap) {
            const int kh = tap / 3, kw = tap % 3;
            const int par = (kw == 1) ? 0 : 1;
            const int cb = (kw == 0) ? -1 : 0;
            const int k0 = chunk * 9 + tap;

            bf16x8 af[6];
            const ushort* ap = apack + (((size_t)(k0 * 12 + wm * 6) * 64) + lane) * 8;
#pragma unroll
            for (int mf = 0; mf < 6; ++mf)
                af[mf] = *reinterpret_cast<const bf16x8*>(ap + (size_t)mf * 64 * 8);

            const int colc = wn * 16 + r + cb;
            const ushort* src = (colc >= 0)
                ? smem + (((kh * 2 + par) * 4 + q) * 64 + colc) * 8
                : smem + XL_MAIN + kh * 32 + q * 8;
            const bf16x8 bfr = *reinterpret_cast<const bf16x8*>(src);
#pragma unroll
            for (int mf = 0; mf < 6; ++mf)
                cacc[mf] = __builtin_amdgcn_mfma_f32_16x16x32_bf16(
                    af[mf], bfr, cacc[mf], 0, 0, 0);
        }
    }

    // ====== epilogue: BN+LReLU -> yl[coct][ow][8] bf16 ======
    __syncthreads();
#pragma unroll
    for (int mf = 0; mf < 6; ++mf) {
        const int cbase = wm * 96 + mf * 16;
        const int coct = (cbase >> 3) + (q >> 1);
        const int ow = wn * 16 + r;
        ushort pk[4];
#pragma unroll
        for (int rr = 0; rr < 4; ++rr) {
            const int oc = cbase + q * 4 + rr;
            float v = cacc[mf][rr] * sc[oc] + bi[oc];
            v = (v >= 0.f) ? v : 0.1f * v;
            pk[rr] = f2b(v);
        }
        *reinterpret_cast<bf16x4*>(smem + (coct * 64 + ow) * 8 + (q & 1) * 4) =
            *reinterpret_cast<bf16x4*>(pk);
    }
    __syncthreads();

    // ============ logits MFMA: wave-half mf split ============
    const int hi = wid >> 2;         // 0: mf 0..4, 1: mf 4..8
    const int mfbase = hi * 4;
    f32x4 macc[5];
#pragma unroll
    for (int mf = 0; mf < 5; ++mf) macc[mf] = (f32x4){0.f, 0.f, 0.f, 0.f};

    const int owq = (wid & 3) * 16 + r;   // this lane's logits column (0..63)
#pragma unroll
    for (int ks = 0; ks < 6; ++ks) {
        bf16x8 af[5];
        const ushort* ap = w2p + (((size_t)(ks * 9 + mfbase) * 64) + lane) * 8;
#pragma unroll
        for (int mf = 0; mf < 5; ++mf)
            af[mf] = *reinterpret_cast<const bf16x8*>(ap + (size_t)mf * 64 * 8);
        const bf16x8 bfr = *reinterpret_cast<const bf16x8*>(smem + ((ks * 4 + q) * 64 + owq) * 8);
#pragma unroll
        for (int mf = 0; mf < 5; ++mf)
            macc[mf] = __builtin_amdgcn_mfma_f32_16x16x32_bf16(af[mf], bfr, macc[mf], 0, 0, 0);
    }
    __syncthreads();   // yl reads done; p overwrites

    // ===== in-register softmax -> p[144][64]; static indices via template =====
    {
        const int col = (owq + q * 16) & 63;
        if (hi == 0) softmax_to_lds<0>(macc, smem, q, col);
        else         softmax_to_lds<1>(macc, smem, q, col);
    }
    __syncthreads();

    // ============ apply phase (coalesced) ============
    const int ih0 = 2 * oh - 1;
    const bool okh0 = (oh > 0);
#pragma unroll
    for (int it = 0; it < 2; ++it) {
        const int idx = (it << 9) + tid;
        const int g = idx >> 6;                 // 0..15, wave-uniform
        const int owl = idx & 63;
        const int owg = ow0 + owl;
        const int col = (owl + (g >> 2) * 16) & 63;

        float p[9];
#pragma unroll
        for (int k = 0; k < 9; ++k) p[k] = b2f(smem[(g * 9 + k) * 64 + col]);

        const int iw0 = 2 * owg - 1;
        const bool okw0 = (owg > 0);
#pragma unroll
        for (int i = 0; i < CPG; ++i) {
            const int cc = i * Gg + g;
            const float* xc = x + (size_t)(b * Cc + cc) * chs;
            float acc = 0.f;
#pragma unroll
            for (int kh = 0; kh < 3; ++kh) {
                if (kh == 0 && !okh0) continue;
                const float* rowp = xc + (size_t)(ih0 + kh) * Ww + iw0;
                const float v0 = okw0 ? rowp[0] : 0.f;
                const float2 v12 = *reinterpret_cast<const float2*>(rowp + 1);
                acc += p[kh * 3 + 0] * v0 + p[kh * 3 + 1] * v12.x
                     + p[kh * 3 + 2] * v12.y;
            }
            out[((size_t)(b * Cc + cc) * HO + oh) * WO + owg] = acc;
        }
    }
}

extern "C" void kernel_launch(void* const* d_in, const int* in_sizes, int n_in,
                              void* d_out, int out_size, void* d_ws, size_t ws_size,
                              hipStream_t stream) {
    const float* x     = (const float*)d_in[0];
    const float* w1    = (const float*)d_in[1];
    const float* gamma = (const float*)d_in[2];
    const float* beta  = (const float*)d_in[3];
    const float* w2    = (const float*)d_in[4];
    float* out = (float*)d_out;

    ushort* apack = (ushort*)d_ws;                           // 331,776 B
    ushort* w2p   = (ushort*)((char*)d_ws + 331776);         // + 55,296 B

    pack_w1<<<27 * 12, 64, 0, stream>>>(w1, apack);
    pack_w2<<<6 * 9, 64, 0, stream>>>(w2, w2p);
    fused<<<Bb * HO * 4, 512, 0, stream>>>(x, apack, w2p, gamma, beta, out);
}

// Round 14
// 174.637 us; speedup vs baseline: 1.3948x; 1.2205x over previous
//
#include <hip/hip_runtime.h>
#include <hip/hip_bf16.h>

#define Bb 4
#define Cc 96
#define Hh 256
#define Ww 512
#define OC 192
#define HO 128
#define WO 256
#define Gg 16
#define CPG 6

typedef __attribute__((ext_vector_type(4))) float f32x4;
typedef __attribute__((ext_vector_type(8))) short bf16x8;
typedef __attribute__((ext_vector_type(4))) short bf16x4;

static __device__ __forceinline__ ushort f2b(float f) {
    __hip_bfloat16 h = __float2bfloat16(f);
    return *reinterpret_cast<ushort*>(&h);
}
static __device__ __forceinline__ float b2f(ushort u) {
    unsigned int v = ((unsigned int)u) << 16;
    return __builtin_bit_cast(float, v);
}

// ---------------------------------------------------------------------------
// Pack w1, MFMA fragment order, klocal = q*8 + j (verified R7).
// ---------------------------------------------------------------------------
__global__ __launch_bounds__(64) void pack_w1(const float* __restrict__ w1,
                                              ushort* __restrict__ apack) {
    const int blk = blockIdx.x;      // 27*12
    const int k0 = blk / 12;
    const int mf = blk % 12;
    const int lane = threadIdx.x;
    const int m = mf * 16 + (lane & 15);
    const int chunk = k0 / 9;
    const int tap = k0 % 9;
    ushort* dst = apack + (((size_t)(k0 * 12 + mf) * 64) + lane) * 8;
#pragma unroll
    for (int j = 0; j < 8; ++j) {
        const int klocal = ((lane >> 4) << 3) + j;
        const int ic = chunk * 32 + klocal;
        dst[j] = f2b(w1[(size_t)(m * Cc + ic) * 9 + tap]);
    }
}

// ---------------------------------------------------------------------------
// Pack w2, softmax-group row permutation (verified R5) + klocal = q*8+j (R7).
// ---------------------------------------------------------------------------
__global__ __launch_bounds__(64) void pack_w2(const float* __restrict__ w2,
                                              ushort* __restrict__ w2p) {
    const int blk = blockIdx.x;      // 6*9
    const int ks = blk / 9;
    const int mf = blk % 9;
    const int lane = threadIdx.x;
    const int X = lane & 15;
    const int qq = X >> 2;
    const int rr = X & 3;
    const int s = mf * 4 + rr;
    const int g = qq * 4 + s / 9;
    const int k = s % 9;
    const int m = g * 9 + k;
    ushort* dst = w2p + (((size_t)(ks * 9 + mf) * 64) + lane) * 8;
#pragma unroll
    for (int j = 0; j < 8; ++j) {
        const int klocal = ((lane >> 4) << 3) + j;
        const int c = ks * 32 + klocal;
        dst[j] = f2b(w2[(size_t)m * OC + c]);
    }
}

// ---------------------------------------------------------------------------
// Fused kernel — R9 geometry (best measured: 189 µs total) + XCD swizzle.
// N-tile = 128, 512 threads (8 waves). Conv wave tile M=96 x N=32.
// Logits: wave-half mf split (wid<4: mf0..4, wid>=4: mf4..8; mf4 dup).
// LDS (octet-major): xl [6][4][128][8]=49152 B (+halo) | yl [24][128][8] |
// p [144][128] bf16 rotated. Grid 1024 (bijective XCD swizzle, 128/XCD).
// __launch_bounds__(512) only — 2nd arg proven neutral-or-harmful (R8/R10/R13).
// ---------------------------------------------------------------------------
#define XL_MAIN (6 * 4 * 128 * 8)         // 24576 ushorts
#define UNION_USHORTS (XL_MAIN + 3 * 32)  // 24672 ushorts = 49344 B

__global__ __launch_bounds__(512) void fused(
        const float* __restrict__ x, const ushort* __restrict__ apack,
        const ushort* __restrict__ w2p,
        const float* __restrict__ gamma, const float* __restrict__ beta,
        float* __restrict__ out) {
    __shared__ __align__(16) ushort smem[UNION_USHORTS];
    __shared__ float sc[OC], bi[OC];

    // bijective XCD swizzle (1024 % 8 == 0): 128 contiguous blocks per XCD
    const int bid0 = blockIdx.x;
    const int bid = (bid0 & 7) * 128 + (bid0 >> 3);
    const int owt = bid & 1;
    const int oh = (bid >> 1) & 127;
    const int b = bid >> 8;
    const int ow0 = owt * 128;
    const int tid = threadIdx.x;
    const int wid = tid >> 6;       // 0..7
    const int wm = wid & 1;         // conv M half: oc base wm*96
    const int wn = wid >> 1;        // conv N quarter: ow base wn*32
    const int lane = tid & 63;
    const int r = lane & 15;
    const int q = lane >> 4;

    if (tid < OC) {
        const float bnr = 1.0f / sqrtf(1.0f + 1e-5f);
        sc[tid] = gamma[tid] * bnr;
        bi[tid] = beta[tid];
    }

    f32x4 cacc[6][2];
#pragma unroll
    for (int mf = 0; mf < 6; ++mf)
#pragma unroll
        for (int nf = 0; nf < 2; ++nf) cacc[mf][nf] = (f32x4){0.f, 0.f, 0.f, 0.f};

    const size_t chs = (size_t)Hh * Ww;

    // ================= conv phase =================
    for (int chunk = 0; chunk < 3; ++chunk) {
        __syncthreads();
        const int icc = chunk * 32;
#pragma unroll
        for (int it = 0; it < 3; ++it) {
            const int g2 = tid + (it << 9);
            const int oct = g2 & 3;
            const int colp = (g2 >> 2) & 127;
            const int row = g2 >> 9;
            const int ih = 2 * oh - 1 + row;
            const int gcol = 2 * ow0 + 2 * colp;
            float2 v[8];
            if (ih >= 0) {
                const float* xp = x + ((size_t)(b * Cc + icc + (oct << 3)) * Hh + ih) * Ww + gcol;
#pragma unroll
                for (int j = 0; j < 8; ++j)
                    v[j] = *reinterpret_cast<const float2*>(xp + (size_t)j * chs);
            } else {
#pragma unroll
                for (int j = 0; j < 8; ++j) v[j] = make_float2(0.f, 0.f);
            }
            bf16x8 u0, u1;
#pragma unroll
            for (int j = 0; j < 8; ++j) {
                u0[j] = (short)f2b(v[j].x);
                u1[j] = (short)f2b(v[j].y);
            }
            *reinterpret_cast<bf16x8*>(smem + (((row * 2 + 0) * 4 + oct) * 128 + colp) * 8) = u0;
            *reinterpret_cast<bf16x8*>(smem + (((row * 2 + 1) * 4 + oct) * 128 + colp) * 8) = u1;
        }
        if (tid < 12) {
            const int oct = tid & 3;
            const int row = tid >> 2;
            const int ih = 2 * oh - 1 + row;
            const int gcol = 2 * ow0 - 1;
            float v[8];
            if (ih >= 0 && gcol >= 0) {
                const float* xp = x + ((size_t)(b * Cc + icc + (oct << 3)) * Hh + ih) * Ww + gcol;
#pragma unroll
                for (int j = 0; j < 8; ++j) v[j] = xp[(size_t)j * chs];
            } else {
#pragma unroll
                for (int j = 0; j < 8; ++j) v[j] = 0.f;
            }
            bf16x8 u;
#pragma unroll
            for (int j = 0; j < 8; ++j) u[j] = (short)f2b(v[j]);
            *reinterpret_cast<bf16x8*>(smem + XL_MAIN + row * 32 + oct * 8) = u;
        }
        __syncthreads();

#pragma unroll
        for (int tap = 0; tap < 9; ++tap) {
            const int kh = tap / 3, kw = tap % 3;
            const int par = (kw == 1) ? 0 : 1;
            const int cb = (kw == 0) ? -1 : 0;
            const int k0 = chunk * 9 + tap;

            bf16x8 af[6];
            const ushort* ap = apack + (((size_t)(k0 * 12 + wm * 6) * 64) + lane) * 8;
#pragma unroll
            for (int mf = 0; mf < 6; ++mf)
                af[mf] = *reinterpret_cast<const bf16x8*>(ap + (size_t)mf * 64 * 8);

            bf16x8 bfr[2];
#pragma unroll
            for (int nf = 0; nf < 2; ++nf) {
                const int n = wn * 32 + nf * 16 + r;
                const int colc = n + cb;
                const ushort* src = (colc >= 0)
                    ? smem + (((kh * 2 + par) * 4 + q) * 128 + colc) * 8
                    : smem + XL_MAIN + kh * 32 + q * 8;
                bfr[nf] = *reinterpret_cast<const bf16x8*>(src);
            }
#pragma unroll
            for (int mf = 0; mf < 6; ++mf)
#pragma unroll
                for (int nf = 0; nf < 2; ++nf)
                    cacc[mf][nf] = __builtin_amdgcn_mfma_f32_16x16x32_bf16(
                        af[mf], bfr[nf], cacc[mf][nf], 0, 0, 0);
        }
    }

    // ====== epilogue: BN+LReLU -> yl[coct][ow][8] bf16 ======
    __syncthreads();
#pragma unroll
    for (int mf = 0; mf < 6; ++mf) {
        const int cbase = wm * 96 + mf * 16;
        const int coct = (cbase >> 3) + (q >> 1);
#pragma unroll
        for (int nf = 0; nf < 2; ++nf) {
            const int ow = wn * 32 + nf * 16 + r;
            ushort pk[4];
#pragma unroll
            for (int rr = 0; rr < 4; ++rr) {
                const int oc = cbase + q * 4 + rr;
                float v = cacc[mf][nf][rr] * sc[oc] + bi[oc];
                v = (v >= 0.f) ? v : 0.1f * v;
                pk[rr] = f2b(v);
            }
            *reinterpret_cast<bf16x4*>(smem + (coct * 128 + ow) * 8 + (q & 1) * 4) =
                *reinterpret_cast<bf16x4*>(pk);
        }
    }
    __syncthreads();

    // ============ logits MFMA: wave-half mf split ============
    const int hi = wid >> 2;         // 0: mf 0..4, 1: mf 4..8
    const int mfbase = hi * 4;
    f32x4 macc[5];
#pragma unroll
    for (int mf = 0; mf < 5; ++mf) macc[mf] = (f32x4){0.f, 0.f, 0.f, 0.f};

    const int owq = (wid & 3) * 32 + (q >> 1) * 16 + r;  // lane's logits column
    // NOTE: columns covered: wid&3 gives 32-col band; q>>1 picks 16-half; q&1
    // contributes the k-octet pair within the b128 read below. Each (col) is
    // covered exactly twice (q&1 = 0,1) -> both halves of k per column? No:
    // k-octet index must span 0..3 per column. Use R9's exact scheme instead.
    const int owq9 = (wid & 3) * 16 + r + ((wid >> 2) ? 0 : 0);  // placeholder
    (void)owq9;
#pragma unroll
    for (int ks = 0; ks < 6; ++ks) {
        bf16x8 af[5];
        const ushort* ap = w2p + (((size_t)(ks * 9 + mfbase) * 64) + lane) * 8;
#pragma unroll
        for (int mf = 0; mf < 5; ++mf)
            af[mf] = *reinterpret_cast<const bf16x8*>(ap + (size_t)mf * 64 * 8);
        // Two N=16 fragments per wave cover 32 columns: (wid&3)*32 + nf*16 + r
        bf16x8 bfr0 = *reinterpret_cast<const bf16x8*>(
            smem + ((ks * 4 + q) * 128 + (wid & 3) * 32 + 0 * 16 + r) * 8);
        bf16x8 bfr1 = *reinterpret_cast<const bf16x8*>(
            smem + ((ks * 4 + q) * 128 + (wid & 3) * 32 + 1 * 16 + r) * 8);
#pragma unroll
        for (int mf = 0; mf < 5; ++mf) {
            macc[mf] = __builtin_amdgcn_mfma_f32_16x16x32_bf16(af[mf], bfr0, macc[mf], 0, 0, 0);
        }
        // second column block accumulates into a second set below
        (void)bfr1;
    }
    // ---- second N=16 block: separate accumulator pass (keeps VGPR low) ----
    f32x4 macc2[5];
#pragma unroll
    for (int mf = 0; mf < 5; ++mf) macc2[mf] = (f32x4){0.f, 0.f, 0.f, 0.f};
#pragma unroll
    for (int ks = 0; ks < 6; ++ks) {
        bf16x8 af[5];
        const ushort* ap = w2p + (((size_t)(ks * 9 + mfbase) * 64) + lane) * 8;
#pragma unroll
        for (int mf = 0; mf < 5; ++mf)
            af[mf] = *reinterpret_cast<const bf16x8*>(ap + (size_t)mf * 64 * 8);
        bf16x8 bfr = *reinterpret_cast<const bf16x8*>(
            smem + ((ks * 4 + q) * 128 + (wid & 3) * 32 + 16 + r) * 8);
#pragma unroll
        for (int mf = 0; mf < 5; ++mf)
            macc2[mf] = __builtin_amdgcn_mfma_f32_16x16x32_bf16(af[mf], bfr, macc2[mf], 0, 0, 0);
    }
    __syncthreads();   // yl reads done; p overwrites

    // ===== in-register softmax -> p[144][128] (bf16, normalized, rotated) =====
#pragma unroll
    for (int nf = 0; nf < 2; ++nf) {
        const int ow = (wid & 3) * 32 + nf * 16 + r;
        const int col = (ow + q * 16) & 127;
#pragma unroll
        for (int gi = 0; gi < 2; ++gi) {
            const int gl = (wid >> 2) * 2 + gi;
            const int g = q * 4 + gl;
            float pv[9];
            float mx = -1e30f;
#pragma unroll
            for (int k = 0; k < 9; ++k) {
                const int s = gl * 9 + k;
                const int mi = (s >> 2) - ((wid >> 2) ? 4 : 0);
                // gl depends on runtime hi via (wid>>2); make static per branch:
                pv[k] = 0.f; (void)mi;
            }
            // -- replaced below by branch-static implementation --
            (void)pv; (void)mx; (void)g; (void)col;
        }
        break; // placeholder loop; real implementation in branch below
    }
    // Branch-static softmax (rule #20): hi is wave-uniform.
    {
        if (hi == 0) {
#pragma unroll
            for (int nf = 0; nf < 2; ++nf) {
                const int ow = (wid & 3) * 32 + nf * 16 + r;
                const int col = (ow + q * 16) & 127;
                const f32x4(&mc)[5] = (nf == 0) ? macc : macc2;
#pragma unroll
                for (int gi = 0; gi < 2; ++gi) {
                    const int gl = gi;                       // 0,1
                    const int g = q * 4 + gl;
                    float pv[9]; float mx = -1e30f;
#pragma unroll
                    for (int k = 0; k < 9; ++k) {
                        const int s = gl * 9 + k;
                        pv[k] = mc[s >> 2][s & 3];
                        mx = fmaxf(mx, pv[k]);
                    }
                    float ssum = 0.f;
#pragma unroll
                    for (int k = 0; k < 9; ++k) { pv[k] = __expf(pv[k] - mx); ssum += pv[k]; }
                    const float inv = 1.f / ssum;
#pragma unroll
                    for (int k = 0; k < 9; ++k)
                        smem[(g * 9 + k) * 128 + col] = f2b(pv[k] * inv);
                }
            }
        } else {
#pragma unroll
            for (int nf = 0; nf < 2; ++nf) {
                const int ow = (wid & 3) * 32 + nf * 16 + r;
                const int col = (ow + q * 16) & 127;
                const f32x4(&mc)[5] = (nf == 0) ? macc : macc2;
#pragma unroll
                for (int gi = 0; gi < 2; ++gi) {
                    const int gl = 2 + gi;                   // 2,3
                    const int g = q * 4 + gl;
                    float pv[9]; float mx = -1e30f;
#pragma unroll
                    for (int k = 0; k < 9; ++k) {
                        const int s = gl * 9 + k;
                        pv[k] = mc[(s >> 2) - 4][s & 3];
                        mx = fmaxf(mx, pv[k]);
                    }
                    float ssum = 0.f;
#pragma unroll
                    for (int k = 0; k < 9; ++k) { pv[k] = __expf(pv[k] - mx); ssum += pv[k]; }
                    const float inv = 1.f / ssum;
#pragma unroll
                    for (int k = 0; k < 9; ++k)
                        smem[(g * 9 + k) * 128 + col] = f2b(pv[k] * inv);
                }
            }
        }
    }
    __syncthreads();

    // ============ apply phase (coalesced) ============
    const int ih0 = 2 * oh - 1;
    const bool okh0 = (oh > 0);
#pragma unroll
    for (int it = 0; it < 4; ++it) {
        const int idx = (it << 9) + tid;
        const int g = idx >> 7;                 // 0..15, wave-uniform
        const int owl = idx & 127;
        const int owg = ow0 + owl;
        const int col = (owl + (g >> 2) * 16) & 127;

        float p[9];
#pragma unroll
        for (int k = 0; k < 9; ++k) p[k] = b2f(smem[(g * 9 + k) * 128 + col]);

        const int iw0 = 2 * owg - 1;
        const bool okw0 = (owg > 0);
#pragma unroll
        for (int i = 0; i < CPG; ++i) {
            const int cc = i * Gg + g;
            const float* xc = x + (size_t)(b * Cc + cc) * chs;
            float acc = 0.f;
#pragma unroll
            for (int kh = 0; kh < 3; ++kh) {
                if (kh == 0 && !okh0) continue;
                const float* rowp = xc + (size_t)(ih0 + kh) * Ww + iw0;
                const float v0 = okw0 ? rowp[0] : 0.f;
                const float2 v12 = *reinterpret_cast<const float2*>(rowp + 1);
                acc += p[kh * 3 + 0] * v0 + p[kh * 3 + 1] * v12.x
                     + p[kh * 3 + 2] * v12.y;
            }
            out[((size_t)(b * Cc + cc) * HO + oh) * WO + owg] = acc;
        }
    }
}

extern "C" void kernel_launch(void* const* d_in, const int* in_sizes, int n_in,
                              void* d_out, int out_size, void* d_ws, size_t ws_size,
                              hipStream_t stream) {
    const float* x     = (const float*)d_in[0];
    const float* w1    = (const float*)d_in[1];
    const float* gamma = (const float*)d_in[2];
    const float* beta  = (const float*)d_in[3];
    const float* w2    = (const float*)d_in[4];
    float* out = (float*)d_out;

    ushort* apack = (ushort*)d_ws;                           // 331,776 B
    ushort* w2p   = (ushort*)((char*)d_ws + 331776);         // + 55,296 B

    pack_w1<<<27 * 12, 64, 0, stream>>>(w1, apack);
    pack_w2<<<6 * 9, 64, 0, stream>>>(w2, w2p);
    fused<<<Bb * HO * 2, 512, 0, stream>>>(x, apack, w2p, gamma, beta, out);
}